// Round 1
// baseline (15266.324 us; speedup 1.0000x reference)
//
#include <hip/hip_runtime.h>
#include <stdint.h>
#include <stdio.h>

typedef unsigned short ushort_t;
typedef float   f32x4  __attribute__((ext_vector_type(4)));
typedef short   bf16x8 __attribute__((ext_vector_type(8)));

#define B_    256
#define T_    256
#define IN_   256
#define HID_  512

// ---------------- workspace layout (bytes) ----------------
#define CTR_WORDS 8448                    // 16 groups * 2 phases * 256 t + abort flag + pad
#define OFF_CTR   0
#define OFF_BT    33792                   // Ball_T  bf16 [1536 n][512 k]   (x|c proj weights, transposed)
#define OFF_WT    1606656                 // wT      bf16 [3][512 j][512 k] (recurrent, transposed + swizzled)
#define OFF_HB    3179520                 // hbuf    bf16 [256][512]
#define OFF_UB    3441664                 // ubuf    bf16 [256][512]
#define OFF_PRE   3703808                 // pre     bf16 [3][T][B][512]
#define WS_NEED   205030400ULL

static __device__ __forceinline__ unsigned short f2bf(float f) {
  union { float f; unsigned u; } v; v.f = f;
  unsigned r = v.u + 0x7FFFu + ((v.u >> 16) & 1u);   // round-to-nearest-even
  return (unsigned short)(r >> 16);
}
static __device__ __forceinline__ float bf2f(unsigned short h) {
  union { unsigned u; float f; } v; v.u = ((unsigned)h) << 16; return v.f;
}
static __device__ __forceinline__ float sigm(float x) {
  float e = exp2f(-1.4426950408889634f * x);
  return __builtin_amdgcn_rcpf(1.0f + e);
}
static __device__ __forceinline__ float tanh_f(float x) {
  float e = exp2f(2.8853900817779268f * x);          // exp(2x)
  return 1.0f - 2.0f * __builtin_amdgcn_rcpf(e + 1.0f);
}

// ================= prep: zero counters, build Ball_T and swizzled wT =================
__global__ void __launch_bounds__(256) k_prep(
    const float* __restrict__ wxz, const float* __restrict__ wxr, const float* __restrict__ wxh,
    const float* __restrict__ wcz, const float* __restrict__ wcr, const float* __restrict__ wch,
    const float* __restrict__ whz, const float* __restrict__ whr, const float* __restrict__ whh,
    unsigned* __restrict__ ctr, ushort_t* __restrict__ bt, ushort_t* __restrict__ wT)
{
  int e = blockIdx.x * 256 + threadIdx.x;          // grid covers 786432 exactly
  if (e < CTR_WORDS) ctr[e] = 0u;

  // Ball_T[n][k]: n = gate*512 + j ; k<256 -> w_x[gate][k][j], k>=256 -> w_c[gate][k-256][j]
  {
    int n = e >> 9, k = e & 511;
    int g = n >> 9, j = n & 511;
    const float* wx = (g == 0) ? wxz : (g == 1) ? wxr : wxh;
    const float* wc = (g == 0) ? wcz : (g == 1) ? wcr : wch;
    float v = (k < 256) ? wx[k * 512 + j] : wc[(k - 256) * 512 + j];
    bt[e] = f2bf(v);
  }
  // wT[g][j][k ^ ((j&7)<<3)] = w_h[g][k][j]   (pre-swizzled for conflict-free ds_read_b128)
  {
    int g = e >> 18, rem = e & 262143;
    int j = rem >> 9, k = rem & 511;
    const float* wh = (g == 0) ? whz : (g == 1) ? whr : whh;
    wT[g * 262144 + j * 512 + (k ^ ((j & 7) << 3))] = f2bf(wh[k * 512 + j]);
  }
}

// ================= pre-GEMM: pre[g][t][b][j] = ([x|c] @ Ball)[bt][g*512+j] + bias =================
__global__ void __launch_bounds__(256) k_pregemm(
    const float* __restrict__ x, const float* __restrict__ c,
    const ushort_t* __restrict__ bt,
    const float* __restrict__ b_z, const float* __restrict__ b_r, const float* __restrict__ b_h,
    ushort_t* __restrict__ pre)
{
  __shared__ ushort_t As[128 * 64];
  __shared__ ushort_t Bs[128 * 64];
  int blk = blockIdx.x;
  int bm = blk % 512, bn = blk / 512;
  int tid = threadIdx.x, lane = tid & 63, wv = tid >> 6;
  int wm = (wv >> 1) * 64, wn = (wv & 1) * 64;
  int cl = lane & 15, rg = lane >> 4;
  f32x4 acc[4][4] = {};

  for (int kt = 0; kt < 8; ++kt) {
    int k0 = kt * 64;
    const float* srcA = (k0 < 256) ? x : c;
    int kbase = (k0 < 256) ? k0 : (k0 - 256);
    #pragma unroll
    for (int i = 0; i < 4; ++i) {                       // stage A (f32 -> bf16, swizzled)
      int ch = tid + 256 * i;
      int m = ch >> 3, k8 = ch & 7;
      const float* p = srcA + (size_t)(bm * 128 + m) * 256 + kbase + k8 * 8;
      float4 f0 = *(const float4*)p;
      float4 f1 = *(const float4*)(p + 4);
      bf16x8 v;
      v[0]=(short)f2bf(f0.x); v[1]=(short)f2bf(f0.y); v[2]=(short)f2bf(f0.z); v[3]=(short)f2bf(f0.w);
      v[4]=(short)f2bf(f1.x); v[5]=(short)f2bf(f1.y); v[6]=(short)f2bf(f1.z); v[7]=(short)f2bf(f1.w);
      *(bf16x8*)((char*)As + ((m * 128 + k8 * 16) ^ ((m & 7) << 4))) = v;
    }
    #pragma unroll
    for (int i = 0; i < 4; ++i) {                       // stage B (pre-swizzled source trick)
      int ch = tid + 256 * i;
      int n = ch >> 3, k8 = ch & 7;
      int k8s = k8 ^ (n & 7);
      bf16x8 v = *(const bf16x8*)(bt + (size_t)(bn * 128 + n) * 512 + k0 + k8s * 8);
      *(bf16x8*)((char*)Bs + (n * 128 + k8 * 16)) = v;
    }
    __syncthreads();
    #pragma unroll
    for (int kk = 0; kk < 2; ++kk) {
      bf16x8 af[4], bfr[4];
      int kb = kk * 32 + rg * 8;
      #pragma unroll
      for (int fm = 0; fm < 4; ++fm) {
        int m = wm + fm * 16 + cl;
        af[fm] = *(const bf16x8*)((char*)As + (((m * 64 + kb) * 2) ^ ((m & 7) << 4)));
      }
      #pragma unroll
      for (int fn = 0; fn < 4; ++fn) {
        int n = wn + fn * 16 + cl;
        bfr[fn] = *(const bf16x8*)((char*)Bs + (((n * 64 + kb) * 2) ^ ((n & 7) << 4)));
      }
      #pragma unroll
      for (int fm = 0; fm < 4; ++fm)
        #pragma unroll
        for (int fn = 0; fn < 4; ++fn)
          acc[fm][fn] = __builtin_amdgcn_mfma_f32_16x16x32_bf16(af[fm], bfr[fn], acc[fm][fn], 0, 0, 0);
    }
    __syncthreads();
  }
  #pragma unroll
  for (int fm = 0; fm < 4; ++fm)
    #pragma unroll
    for (int fn = 0; fn < 4; ++fn) {
      int ng = bn * 128 + wn + fn * 16 + cl;
      int g = ng >> 9, j = ng & 511;
      const float* bias = (g == 0) ? b_z : (g == 1) ? b_r : b_h;
      float bv = bias[j];
      #pragma unroll
      for (int i = 0; i < 4; ++i) {
        int M = bm * 128 + wm + fm * 16 + rg * 4 + i;   // M = b*T + t
        int b = M >> 8, t = M & 255;
        pre[(((size_t)g * 256 + t) * 256 + b) * 512 + j] = f2bf(acc[fm][fn][i] + bv);
      }
    }
}

// ================= scan =================
struct ScanArgs {
  const ushort_t* wT;
  const ushort_t* pre;
  ushort_t* hbuf;       // bf16 [256][512] exchange
  ushort_t* ubuf;       // bf16 [256][512] exchange
  unsigned* ctr;
  const float* h0;
  float* hs;            // d_out + 65536, [B][T][512] f32
};
#define SMEM_SCAN 133120

static __device__ __forceinline__ void fill_swz_bf16(const ushort_t* __restrict__ src,
                                                     ushort_t* dst, int tid) {
  #pragma unroll
  for (int i = 0; i < 4; ++i) {
    int ch = tid + 256 * i;
    int row = ch >> 6, k8 = ch & 63;
    bf16x8 v = *(const bf16x8*)(src + (size_t)row * 512 + k8 * 8);
    *(bf16x8*)((char*)dst + (((row * 512 + k8 * 8) * 2) ^ ((row & 7) << 4))) = v;
  }
}
static __device__ __forceinline__ void fill_init(const float* __restrict__ src,
                                                 ushort_t* hA, float* hsl, int J, int tid) {
  #pragma unroll
  for (int i = 0; i < 4; ++i) {
    int ch = tid + 256 * i;
    int row = ch >> 6, k8 = ch & 63;
    const float* p = src + (size_t)row * 512 + k8 * 8;
    float4 f0 = *(const float4*)p;
    float4 f1 = *(const float4*)(p + 4);
    bf16x8 v;
    v[0]=(short)f2bf(f0.x); v[1]=(short)f2bf(f0.y); v[2]=(short)f2bf(f0.z); v[3]=(short)f2bf(f0.w);
    v[4]=(short)f2bf(f1.x); v[5]=(short)f2bf(f1.y); v[6]=(short)f2bf(f1.z); v[7]=(short)f2bf(f1.w);
    *(bf16x8*)((char*)hA + (((row * 512 + k8 * 8) * 2) ^ ((row & 7) << 4))) = v;
    int kb = k8 * 8;
    if (kb >= J && kb < J + 32) {
      float* q = hsl + row * 32 + (kb - J);
      q[0]=f0.x; q[1]=f0.y; q[2]=f0.z; q[3]=f0.w; q[4]=f1.x; q[5]=f1.y; q[6]=f1.z; q[7]=f1.w;
    }
  }
}
static __device__ __forceinline__ void gbarrier(unsigned* c, unsigned* abortf, bool& dead) {
  __threadfence();               // drain this thread's global stores to coherence point
  __syncthreads();               // all threads' fences complete before leader arrives
  if (threadIdx.x == 0) {
    if (!dead) {
      __hip_atomic_fetch_add(c, 1u, __ATOMIC_RELEASE, __HIP_MEMORY_SCOPE_AGENT);
      unsigned it = 0;
      while (__hip_atomic_load(c, __ATOMIC_ACQUIRE, __HIP_MEMORY_SCOPE_AGENT) < 16u) {
        __builtin_amdgcn_s_sleep(1);
        if (((++it) & 255u) == 0u) {
          if (it > (1u << 21)) { __hip_atomic_store(abortf, 1u, __ATOMIC_RELAXED, __HIP_MEMORY_SCOPE_AGENT); dead = true; break; }
          if (__hip_atomic_load(abortf, __ATOMIC_RELAXED, __HIP_MEMORY_SCOPE_AGENT) != 0u) { dead = true; break; }
        }
      }
    }
  }
  __syncthreads();
}

__global__ void __launch_bounds__(256, 1) k_scan(ScanArgs A) {
  extern __shared__ char smem[];
  ushort_t* Wt  = (ushort_t*)smem;              // [3][32][512] bf16 swizzled
  ushort_t* hA  = (ushort_t*)(smem + 98304);    // [16][512] bf16 swizzled
  ushort_t* uA  = (ushort_t*)(smem + 114688);   // [16][512] bf16 swizzled
  float*    hsl = (float*)(smem + 131072);      // [16][32] f32 (own j-slice of h)

  int blk = blockIdx.x;
  int g = blk & 15, wgj = blk >> 4;
  int J = wgj * 32;
  int b0 = g * 16;
  int tid = threadIdx.x, lane = tid & 63, wv = tid >> 6;
  int cl = lane & 15, rg = lane >> 4;
  unsigned* ctrU = A.ctr + (g * 2 + 0) * 256;
  unsigned* ctrH = A.ctr + (g * 2 + 1) * 256;
  unsigned* abortf = A.ctr + 16 * 2 * 256;
  bool dead = false;

  // one-time: copy this WG's weight slices (already transposed+swizzled in ws)
  #pragma unroll
  for (int gt = 0; gt < 3; ++gt) {
    const ushort_t* src = A.wT + gt * 262144 + J * 512;
    ushort_t* dst = Wt + gt * 16384;
    #pragma unroll
    for (int i = 0; i < 8; ++i) {
      int ch = tid + 256 * i;
      *(bf16x8*)(dst + ch * 8) = *(const bf16x8*)(src + ch * 8);
    }
  }
  fill_init(A.h0 + (size_t)b0 * 512, hA, hsl, J, tid);
  __syncthreads();

  #pragma unroll 1
  for (int t = 0; t < 256; ++t) {
    // ---- prefetch pre (bf16, direct) ----
    float pg[4], ph[4];
    {
      int gate1 = wv >> 1;
      int col = J + (wv & 1) * 16 + cl;
      const ushort_t* pp  = A.pre + (((size_t)gate1 * 256 + t) * 256 + b0) * 512;
      const ushort_t* pph = A.pre + (((size_t)2 * 256 + t) * 256 + b0) * 512;
      #pragma unroll
      for (int i = 0; i < 4; ++i) {
        int row = rg * 4 + i;
        pg[i] = bf2f(pp[(size_t)row * 512 + col]);
        ph[i] = (wv < 2) ? bf2f(pph[(size_t)row * 512 + col]) : 0.0f;
      }
    }
    // ---- phase 1: z (waves 0,1) and r (waves 2,3), K=512 ----
    int gate = wv >> 1;
    int jl = (wv & 1) * 16 + cl;
    f32x4 acc = {};
    #pragma unroll
    for (int kk = 0; kk < 16; ++kk) {
      int kb = kk * 32 + rg * 8;
      bf16x8 av = *(const bf16x8*)((char*)hA + (((cl * 512 + kb) * 2) ^ ((cl & 7) << 4)));
      bf16x8 bv = *(const bf16x8*)((char*)Wt + gate * 32768 + (((jl * 512 + kb) * 2) ^ ((jl & 7) << 4)));
      acc = __builtin_amdgcn_mfma_f32_16x16x32_bf16(av, bv, acc, 0, 0, 0);
    }
    float zv[4] = {0.f, 0.f, 0.f, 0.f};
    if (wv < 2) {
      #pragma unroll
      for (int i = 0; i < 4; ++i) zv[i] = sigm(acc[i] + pg[i]);
    } else {
      #pragma unroll
      for (int i = 0; i < 4; ++i) {
        float r = sigm(acc[i] + pg[i]);
        int row = rg * 4 + i;
        float u = r * hsl[row * 32 + jl];
        A.ubuf[(size_t)(b0 + row) * 512 + J + jl] = f2bf(u);
      }
    }
    gbarrier(ctrU + t, abortf, dead);
    fill_swz_bf16(A.ubuf + (size_t)b0 * 512, uA, tid);
    __syncthreads();
    // ---- phase 2: h_tilde + h_new (waves 0,1) ----
    if (wv < 2) {
      f32x4 acc2 = {};
      int jl2 = wv * 16 + cl;
      #pragma unroll
      for (int kk = 0; kk < 16; ++kk) {
        int kb = kk * 32 + rg * 8;
        bf16x8 av = *(const bf16x8*)((char*)uA + (((cl * 512 + kb) * 2) ^ ((cl & 7) << 4)));
        bf16x8 bv = *(const bf16x8*)((char*)Wt + 2 * 32768 + (((jl2 * 512 + kb) * 2) ^ ((jl2 & 7) << 4)));
        acc2 = __builtin_amdgcn_mfma_f32_16x16x32_bf16(av, bv, acc2, 0, 0, 0);
      }
      #pragma unroll
      for (int i = 0; i < 4; ++i) {
        int row = rg * 4 + i;
        float th = tanh_f(acc2[i] + ph[i]);
        float hv = hsl[row * 32 + jl2];
        float hn = hv + zv[i] * (th - hv);
        hsl[row * 32 + jl2] = hn;                                  // own f32 copy for next step
        int b = b0 + row;
        A.hbuf[(size_t)b * 512 + J + jl2] = f2bf(hn);
        A.hs[((size_t)b * 256 + t) * 512 + J + jl2] = hn;
      }
    }
    gbarrier(ctrH + t, abortf, dead);
    fill_swz_bf16(A.hbuf + (size_t)b0 * 512, hA, tid);
    __syncthreads();
  }
}

// ================= out projection =================
__global__ void __launch_bounds__(256) k_out(const float* __restrict__ hs,
                                             const float* __restrict__ w_out,
                                             const float* __restrict__ b_out,
                                             float* __restrict__ out) {
  __shared__ float hl[512];
  int b = blockIdx.x, o = threadIdx.x;
  const float* hrow = hs + ((size_t)b * 256 + 255) * 512;
  for (int i = threadIdx.x; i < 512; i += 256) hl[i] = hrow[i];
  __syncthreads();
  float acc = b_out[o];
  #pragma unroll 8
  for (int k = 0; k < 512; ++k) acc += hl[k] * w_out[k * 256 + o];
  out[(size_t)b * 256 + o] = fmaxf(acc, 0.0f);
}

// ================= host =================
extern "C" void kernel_launch(void* const* d_in, const int* in_sizes, int n_in,
                              void* d_out, int out_size, void* d_ws, size_t ws_size,
                              hipStream_t stream) {
  const float* x    = (const float*)d_in[0];
  const float* c    = (const float*)d_in[1];
  const float* h0   = (const float*)d_in[2];
  const float* wxr  = (const float*)d_in[3];
  const float* whr  = (const float*)d_in[4];
  const float* wcr  = (const float*)d_in[5];
  const float* wxz  = (const float*)d_in[6];
  const float* whz  = (const float*)d_in[7];
  const float* wcz  = (const float*)d_in[8];
  const float* wxh  = (const float*)d_in[9];
  const float* whh  = (const float*)d_in[10];
  const float* wch  = (const float*)d_in[11];
  const float* br   = (const float*)d_in[12];
  const float* bz   = (const float*)d_in[13];
  const float* bh   = (const float*)d_in[14];
  const float* wout = (const float*)d_in[15];
  const float* bout = (const float*)d_in[16];

  char* ws = (char*)d_ws;
  unsigned*  ctr  = (unsigned*)(ws + OFF_CTR);
  ushort_t*  bt   = (ushort_t*)(ws + OFF_BT);
  ushort_t*  wT   = (ushort_t*)(ws + OFF_WT);
  ushort_t*  hbuf = (ushort_t*)(ws + OFF_HB);
  ushort_t*  ubuf = (ushort_t*)(ws + OFF_UB);
  ushort_t*  pre  = (ushort_t*)(ws + OFF_PRE);
  float* out = (float*)d_out;
  float* hs  = out + 65536;

  if (ws_size < WS_NEED)
    fprintf(stderr, "[kernel] WARNING ws_size=%zu < needed %llu\n", ws_size, WS_NEED);

  k_prep<<<3072, 256, 0, stream>>>(wxz, wxr, wxh, wcz, wcr, wch, whz, whr, whh, ctr, bt, wT);
  k_pregemm<<<6144, 256, 0, stream>>>(x, c, bt, bz, br, bh, pre);

  hipFuncSetAttribute((const void*)k_scan, hipFuncAttributeMaxDynamicSharedMemorySize, SMEM_SCAN);
  ScanArgs sa{wT, pre, hbuf, ubuf, ctr, h0, hs};
  void* args[] = { &sa };
  hipError_t e = hipLaunchCooperativeKernel(k_scan, dim3(256), dim3(256), args,
                                            (unsigned)SMEM_SCAN, stream);
  if (e != hipSuccess)
    fprintf(stderr, "[kernel] coop launch failed: %d (%s)\n", (int)e, hipGetErrorString(e));

  k_out<<<256, 256, 0, stream>>>(hs, wout, bout, out);
}

// Round 2
// 1979.320 us; speedup vs baseline: 7.7129x; 7.7129x over previous
//
#include <hip/hip_runtime.h>
#include <stdint.h>
#include <stdio.h>

typedef unsigned short ushort_t;
typedef float   f32x4  __attribute__((ext_vector_type(4)));
typedef short   bf16x8 __attribute__((ext_vector_type(8)));

#define B_    256
#define T_    256
#define IN_   256
#define HID_  512

// ---------------- workspace layout (bytes) ----------------
#define CTR_WORDS 8448                    // 16 groups * 2 phases * 256 t + abort flag + pad
#define OFF_CTR   0
#define OFF_BT    33792                   // Ball_T  bf16 [1536 n][512 k]   (x|c proj weights, transposed)
#define OFF_WT    1606656                 // wT      bf16 [3][512 j][512 k] (recurrent, transposed + swizzled)
#define OFF_HB    3179520                 // hbuf    bf16 [256][512]
#define OFF_UB    3441664                 // ubuf    bf16 [256][512]
#define OFF_PRE   3703808                 // pre     bf16 [3][T][B][512]
#define WS_NEED   205030400ULL

static __device__ __forceinline__ unsigned short f2bf(float f) {
  union { float f; unsigned u; } v; v.f = f;
  unsigned r = v.u + 0x7FFFu + ((v.u >> 16) & 1u);   // round-to-nearest-even
  return (unsigned short)(r >> 16);
}
static __device__ __forceinline__ float bf2f(unsigned short h) {
  union { unsigned u; float f; } v; v.u = ((unsigned)h) << 16; return v.f;
}
static __device__ __forceinline__ float sigm(float x) {
  float e = exp2f(-1.4426950408889634f * x);
  return __builtin_amdgcn_rcpf(1.0f + e);
}
static __device__ __forceinline__ float tanh_f(float x) {
  float e = exp2f(2.8853900817779268f * x);          // exp(2x)
  return 1.0f - 2.0f * __builtin_amdgcn_rcpf(e + 1.0f);
}

// ---- device-coherent (write-through, cache-bypassing) accessors: no wbl2/inv needed ----
static __device__ __forceinline__ void st_b16_dev(void* p, unsigned v) {
  asm volatile("global_store_short %0, %1, off sc0 sc1" :: "v"(p), "v"(v) : "memory");
}
static __device__ __forceinline__ void ld4_b128_dev(const void* p0, const void* p1,
                                                    const void* p2, const void* p3,
                                                    f32x4& a, f32x4& b, f32x4& c, f32x4& d) {
  asm volatile("global_load_dwordx4 %0, %4, off sc0 sc1\n\t"
               "global_load_dwordx4 %1, %5, off sc0 sc1\n\t"
               "global_load_dwordx4 %2, %6, off sc0 sc1\n\t"
               "global_load_dwordx4 %3, %7, off sc0 sc1\n\t"
               "s_waitcnt vmcnt(0)"
               : "=&v"(a), "=&v"(b), "=&v"(c), "=&v"(d)
               : "v"(p0), "v"(p1), "v"(p2), "v"(p3)
               : "memory");
}

// ================= prep: zero counters, build Ball_T and swizzled wT =================
__global__ void __launch_bounds__(256) k_prep(
    const float* __restrict__ wxz, const float* __restrict__ wxr, const float* __restrict__ wxh,
    const float* __restrict__ wcz, const float* __restrict__ wcr, const float* __restrict__ wch,
    const float* __restrict__ whz, const float* __restrict__ whr, const float* __restrict__ whh,
    unsigned* __restrict__ ctr, ushort_t* __restrict__ bt, ushort_t* __restrict__ wT)
{
  int e = blockIdx.x * 256 + threadIdx.x;          // grid covers 786432 exactly
  if (e < CTR_WORDS) ctr[e] = 0u;

  // Ball_T[n][k]: n = gate*512 + j ; k<256 -> w_x[gate][k][j], k>=256 -> w_c[gate][k-256][j]
  {
    int n = e >> 9, k = e & 511;
    int g = n >> 9, j = n & 511;
    const float* wx = (g == 0) ? wxz : (g == 1) ? wxr : wxh;
    const float* wc = (g == 0) ? wcz : (g == 1) ? wcr : wch;
    float v = (k < 256) ? wx[k * 512 + j] : wc[(k - 256) * 512 + j];
    bt[e] = f2bf(v);
  }
  // wT[g][j][k ^ ((j&7)<<3)] = w_h[g][k][j]   (pre-swizzled for conflict-free ds_read_b128)
  {
    int g = e >> 18, rem = e & 262143;
    int j = rem >> 9, k = rem & 511;
    const float* wh = (g == 0) ? whz : (g == 1) ? whr : whh;
    wT[g * 262144 + j * 512 + (k ^ ((j & 7) << 3))] = f2bf(wh[k * 512 + j]);
  }
}

// ================= pre-GEMM: pre[g][t][b][j] = ([x|c] @ Ball)[bt][g*512+j] + bias =================
__global__ void __launch_bounds__(256) k_pregemm(
    const float* __restrict__ x, const float* __restrict__ c,
    const ushort_t* __restrict__ bt,
    const float* __restrict__ b_z, const float* __restrict__ b_r, const float* __restrict__ b_h,
    ushort_t* __restrict__ pre)
{
  __shared__ ushort_t As[128 * 64];
  __shared__ ushort_t Bs[128 * 64];
  int blk = blockIdx.x;
  int bm = blk % 512, bn = blk / 512;
  int tid = threadIdx.x, lane = tid & 63, wv = tid >> 6;
  int wm = (wv >> 1) * 64, wn = (wv & 1) * 64;
  int cl = lane & 15, rg = lane >> 4;
  f32x4 acc[4][4] = {};

  for (int kt = 0; kt < 8; ++kt) {
    int k0 = kt * 64;
    const float* srcA = (k0 < 256) ? x : c;
    int kbase = (k0 < 256) ? k0 : (k0 - 256);
    #pragma unroll
    for (int i = 0; i < 4; ++i) {                       // stage A (f32 -> bf16, swizzled)
      int ch = tid + 256 * i;
      int m = ch >> 3, k8 = ch & 7;
      const float* p = srcA + (size_t)(bm * 128 + m) * 256 + kbase + k8 * 8;
      float4 f0 = *(const float4*)p;
      float4 f1 = *(const float4*)(p + 4);
      bf16x8 v;
      v[0]=(short)f2bf(f0.x); v[1]=(short)f2bf(f0.y); v[2]=(short)f2bf(f0.z); v[3]=(short)f2bf(f0.w);
      v[4]=(short)f2bf(f1.x); v[5]=(short)f2bf(f1.y); v[6]=(short)f2bf(f1.z); v[7]=(short)f2bf(f1.w);
      *(bf16x8*)((char*)As + ((m * 128 + k8 * 16) ^ ((m & 7) << 4))) = v;
    }
    #pragma unroll
    for (int i = 0; i < 4; ++i) {                       // stage B (pre-swizzled source trick)
      int ch = tid + 256 * i;
      int n = ch >> 3, k8 = ch & 7;
      int k8s = k8 ^ (n & 7);
      bf16x8 v = *(const bf16x8*)(bt + (size_t)(bn * 128 + n) * 512 + k0 + k8s * 8);
      *(bf16x8*)((char*)Bs + (n * 128 + k8 * 16)) = v;
    }
    __syncthreads();
    #pragma unroll
    for (int kk = 0; kk < 2; ++kk) {
      bf16x8 af[4], bfr[4];
      int kb = kk * 32 + rg * 8;
      #pragma unroll
      for (int fm = 0; fm < 4; ++fm) {
        int m = wm + fm * 16 + cl;
        af[fm] = *(const bf16x8*)((char*)As + (((m * 64 + kb) * 2) ^ ((m & 7) << 4)));
      }
      #pragma unroll
      for (int fn = 0; fn < 4; ++fn) {
        int n = wn + fn * 16 + cl;
        bfr[fn] = *(const bf16x8*)((char*)Bs + (((n * 64 + kb) * 2) ^ ((n & 7) << 4)));
      }
      #pragma unroll
      for (int fm = 0; fm < 4; ++fm)
        #pragma unroll
        for (int fn = 0; fn < 4; ++fn)
          acc[fm][fn] = __builtin_amdgcn_mfma_f32_16x16x32_bf16(af[fm], bfr[fn], acc[fm][fn], 0, 0, 0);
    }
    __syncthreads();
  }
  #pragma unroll
  for (int fm = 0; fm < 4; ++fm)
    #pragma unroll
    for (int fn = 0; fn < 4; ++fn) {
      int ng = bn * 128 + wn + fn * 16 + cl;
      int g = ng >> 9, j = ng & 511;
      const float* bias = (g == 0) ? b_z : (g == 1) ? b_r : b_h;
      float bv = bias[j];
      #pragma unroll
      for (int i = 0; i < 4; ++i) {
        int M = bm * 128 + wm + fm * 16 + rg * 4 + i;   // M = b*T + t
        int b = M >> 8, t = M & 255;
        pre[(((size_t)g * 256 + t) * 256 + b) * 512 + j] = f2bf(acc[fm][fn][i] + bv);
      }
    }
}

// ================= scan =================
struct ScanArgs {
  const ushort_t* wT;
  const ushort_t* pre;
  ushort_t* hbuf;       // bf16 [256][512] exchange (write-through only)
  ushort_t* ubuf;       // bf16 [256][512] exchange (write-through only)
  unsigned* ctr;
  const float* h0;
  float* hs;            // d_out + 65536, [B][T][512] f32
};
#define SMEM_SCAN 133120

// read 16x512 bf16 exchange tile via L3-direct loads, swizzle-store into LDS
static __device__ __forceinline__ void xchg_read_swz(const ushort_t* __restrict__ src,
                                                     ushort_t* dst, int tid) {
  const void* p[4];
  f32x4 v0, v1, v2, v3;
  #pragma unroll
  for (int i = 0; i < 4; ++i) { int ch = tid + 256 * i; p[i] = src + (size_t)ch * 8; }
  ld4_b128_dev(p[0], p[1], p[2], p[3], v0, v1, v2, v3);
  f32x4 vv[4] = { v0, v1, v2, v3 };
  #pragma unroll
  for (int i = 0; i < 4; ++i) {
    int ch = tid + 256 * i;
    int row = ch >> 6, k8 = ch & 63;
    *(f32x4*)((char*)dst + (((row * 512 + k8 * 8) * 2) ^ ((row & 7) << 4))) = vv[i];
  }
}

static __device__ __forceinline__ void fill_init(const float* __restrict__ src,
                                                 ushort_t* hA, float* hsl, int J, int tid) {
  #pragma unroll
  for (int i = 0; i < 4; ++i) {
    int ch = tid + 256 * i;
    int row = ch >> 6, k8 = ch & 63;
    const float* p = src + (size_t)row * 512 + k8 * 8;
    float4 f0 = *(const float4*)p;
    float4 f1 = *(const float4*)(p + 4);
    bf16x8 v;
    v[0]=(short)f2bf(f0.x); v[1]=(short)f2bf(f0.y); v[2]=(short)f2bf(f0.z); v[3]=(short)f2bf(f0.w);
    v[4]=(short)f2bf(f1.x); v[5]=(short)f2bf(f1.y); v[6]=(short)f2bf(f1.z); v[7]=(short)f2bf(f1.w);
    *(bf16x8*)((char*)hA + (((row * 512 + k8 * 8) * 2) ^ ((row & 7) << 4))) = v;
    int kb = k8 * 8;
    if (kb >= J && kb < J + 32) {
      float* q = hsl + row * 32 + (kb - J);
      q[0]=f0.x; q[1]=f0.y; q[2]=f0.z; q[3]=f0.w; q[4]=f1.x; q[5]=f1.y; q[6]=f1.z; q[7]=f1.w;
    }
  }
}

// leader-only: relaxed signal + relaxed poll (no cache-maintenance ops at all)
static __device__ __forceinline__ void signal_wait(unsigned* c, unsigned* abortf, bool& dead) {
  if (dead) return;
  __hip_atomic_fetch_add(c, 1u, __ATOMIC_RELAXED, __HIP_MEMORY_SCOPE_AGENT);
  unsigned it = 0;
  while (__hip_atomic_load(c, __ATOMIC_RELAXED, __HIP_MEMORY_SCOPE_AGENT) < 16u) {
    if (((++it) & 63u) == 0u) {
      if (it > (1u << 18)) { __hip_atomic_store(abortf, 1u, __ATOMIC_RELAXED, __HIP_MEMORY_SCOPE_AGENT); dead = true; break; }
      if (__hip_atomic_load(abortf, __ATOMIC_RELAXED, __HIP_MEMORY_SCOPE_AGENT) != 0u) { dead = true; break; }
    }
  }
}

__global__ void __launch_bounds__(256, 1) k_scan(ScanArgs A) {
  extern __shared__ char smem[];
  ushort_t* Wt  = (ushort_t*)smem;              // [3][32][512] bf16 swizzled
  ushort_t* hA  = (ushort_t*)(smem + 98304);    // [16][512] bf16 swizzled
  ushort_t* uA  = (ushort_t*)(smem + 114688);   // [16][512] bf16 swizzled
  float*    hsl = (float*)(smem + 131072);      // [16][32] f32 (own j-slice of h)

  int blk = blockIdx.x;
  int g = blk & 15, wgj = blk >> 4;
  int J = wgj * 32;
  int b0 = g * 16;
  int tid = threadIdx.x, lane = tid & 63, wv = tid >> 6;
  int cl = lane & 15, rg = lane >> 4;
  unsigned* ctrU = A.ctr + (g * 2 + 0) * 256;
  unsigned* ctrH = A.ctr + (g * 2 + 1) * 256;
  unsigned* abortf = A.ctr + 16 * 2 * 256;
  bool dead = false;

  // one-time: copy this WG's weight slices (already transposed+swizzled in ws)
  #pragma unroll
  for (int gt = 0; gt < 3; ++gt) {
    const ushort_t* src = A.wT + gt * 262144 + J * 512;
    ushort_t* dst = Wt + gt * 16384;
    #pragma unroll
    for (int i = 0; i < 8; ++i) {
      int ch = tid + 256 * i;
      *(bf16x8*)(dst + ch * 8) = *(const bf16x8*)(src + ch * 8);
    }
  }
  fill_init(A.h0 + (size_t)b0 * 512, hA, hsl, J, tid);
  __syncthreads();

  #pragma unroll 1
  for (int t = 0; t < 256; ++t) {
    // ---- prefetch pre (bf16, cached loads; overlap with phase-1 MFMA) ----
    float pg[4], ph[4];
    {
      int gate1 = wv >> 1;
      int col = J + (wv & 1) * 16 + cl;
      const ushort_t* pp  = A.pre + (((size_t)gate1 * 256 + t) * 256 + b0) * 512;
      const ushort_t* pph = A.pre + (((size_t)2 * 256 + t) * 256 + b0) * 512;
      #pragma unroll
      for (int i = 0; i < 4; ++i) {
        int row = rg * 4 + i;
        pg[i] = bf2f(pp[(size_t)row * 512 + col]);
        ph[i] = (wv < 2) ? bf2f(pph[(size_t)row * 512 + col]) : 0.0f;
      }
    }
    // ---- phase 1: z (waves 0,1) and r (waves 2,3), K=512 ----
    int gate = wv >> 1;
    int jl = (wv & 1) * 16 + cl;
    f32x4 acc = {};
    #pragma unroll
    for (int kk = 0; kk < 16; ++kk) {
      int kb = kk * 32 + rg * 8;
      bf16x8 av = *(const bf16x8*)((char*)hA + (((cl * 512 + kb) * 2) ^ ((cl & 7) << 4)));
      bf16x8 bv = *(const bf16x8*)((char*)Wt + gate * 32768 + (((jl * 512 + kb) * 2) ^ ((jl & 7) << 4)));
      acc = __builtin_amdgcn_mfma_f32_16x16x32_bf16(av, bv, acc, 0, 0, 0);
    }
    float zv[4] = {0.f, 0.f, 0.f, 0.f};
    if (wv < 2) {
      #pragma unroll
      for (int i = 0; i < 4; ++i) zv[i] = sigm(acc[i] + pg[i]);
    } else {
      #pragma unroll
      for (int i = 0; i < 4; ++i) {
        float r = sigm(acc[i] + pg[i]);
        int row = rg * 4 + i;
        float u = r * hsl[row * 32 + jl];
        st_b16_dev(A.ubuf + (size_t)(b0 + row) * 512 + J + jl, (unsigned)f2bf(u));
      }
    }
    asm volatile("s_waitcnt vmcnt(0)" ::: "memory");   // write-through stores visible at L3
    __syncthreads();
    if (tid == 0) signal_wait(ctrU + t, abortf, dead);
    __syncthreads();
    xchg_read_swz(A.ubuf + (size_t)b0 * 512, uA, tid);
    __syncthreads();
    // ---- phase 2: h_tilde + h_new (waves 0,1) ----
    if (wv < 2) {
      f32x4 acc2 = {};
      int jl2 = wv * 16 + cl;
      #pragma unroll
      for (int kk = 0; kk < 16; ++kk) {
        int kb = kk * 32 + rg * 8;
        bf16x8 av = *(const bf16x8*)((char*)uA + (((cl * 512 + kb) * 2) ^ ((cl & 7) << 4)));
        bf16x8 bv = *(const bf16x8*)((char*)Wt + 2 * 32768 + (((jl2 * 512 + kb) * 2) ^ ((jl2 & 7) << 4)));
        acc2 = __builtin_amdgcn_mfma_f32_16x16x32_bf16(av, bv, acc2, 0, 0, 0);
      }
      #pragma unroll
      for (int i = 0; i < 4; ++i) {
        int row = rg * 4 + i;
        float th = tanh_f(acc2[i] + ph[i]);
        float hv = hsl[row * 32 + jl2];
        float hn = hv + zv[i] * (th - hv);
        hsl[row * 32 + jl2] = hn;                                  // own f32 copy for next step
        int b = b0 + row;
        st_b16_dev(A.hbuf + (size_t)b * 512 + J + jl2, (unsigned)f2bf(hn));
        A.hs[((size_t)b * 256 + t) * 512 + J + jl2] = hn;          // normal cached store
      }
    }
    asm volatile("s_waitcnt vmcnt(0)" ::: "memory");
    __syncthreads();
    if (tid == 0) signal_wait(ctrH + t, abortf, dead);
    __syncthreads();
    xchg_read_swz(A.hbuf + (size_t)b0 * 512, hA, tid);
    __syncthreads();
  }
}

// ================= out projection =================
__global__ void __launch_bounds__(256) k_out(const float* __restrict__ hs,
                                             const float* __restrict__ w_out,
                                             const float* __restrict__ b_out,
                                             float* __restrict__ out) {
  __shared__ float hl[512];
  int b = blockIdx.x, o = threadIdx.x;
  const float* hrow = hs + ((size_t)b * 256 + 255) * 512;
  for (int i = threadIdx.x; i < 512; i += 256) hl[i] = hrow[i];
  __syncthreads();
  float acc = b_out[o];
  #pragma unroll 8
  for (int k = 0; k < 512; ++k) acc += hl[k] * w_out[k * 256 + o];
  out[(size_t)b * 256 + o] = fmaxf(acc, 0.0f);
}

// ================= host =================
extern "C" void kernel_launch(void* const* d_in, const int* in_sizes, int n_in,
                              void* d_out, int out_size, void* d_ws, size_t ws_size,
                              hipStream_t stream) {
  const float* x    = (const float*)d_in[0];
  const float* c    = (const float*)d_in[1];
  const float* h0   = (const float*)d_in[2];
  const float* wxr  = (const float*)d_in[3];
  const float* whr  = (const float*)d_in[4];
  const float* wcr  = (const float*)d_in[5];
  const float* wxz  = (const float*)d_in[6];
  const float* whz  = (const float*)d_in[7];
  const float* wcz  = (const float*)d_in[8];
  const float* wxh  = (const float*)d_in[9];
  const float* whh  = (const float*)d_in[10];
  const float* wch  = (const float*)d_in[11];
  const float* br   = (const float*)d_in[12];
  const float* bz   = (const float*)d_in[13];
  const float* bh   = (const float*)d_in[14];
  const float* wout = (const float*)d_in[15];
  const float* bout = (const float*)d_in[16];

  char* ws = (char*)d_ws;
  unsigned*  ctr  = (unsigned*)(ws + OFF_CTR);
  ushort_t*  bt   = (ushort_t*)(ws + OFF_BT);
  ushort_t*  wT   = (ushort_t*)(ws + OFF_WT);
  ushort_t*  hbuf = (ushort_t*)(ws + OFF_HB);
  ushort_t*  ubuf = (ushort_t*)(ws + OFF_UB);
  ushort_t*  pre  = (ushort_t*)(ws + OFF_PRE);
  float* out = (float*)d_out;
  float* hs  = out + 65536;

  if (ws_size < WS_NEED)
    fprintf(stderr, "[kernel] WARNING ws_size=%zu < needed %llu\n", ws_size, WS_NEED);

  k_prep<<<3072, 256, 0, stream>>>(wxz, wxr, wxh, wcz, wcr, wch, whz, whr, whh, ctr, bt, wT);
  k_pregemm<<<6144, 256, 0, stream>>>(x, c, bt, bz, br, bh, pre);

  hipFuncSetAttribute((const void*)k_scan, hipFuncAttributeMaxDynamicSharedMemorySize, SMEM_SCAN);
  ScanArgs sa{wT, pre, hbuf, ubuf, ctr, h0, hs};
  void* args[] = { &sa };
  hipError_t e = hipLaunchCooperativeKernel(k_scan, dim3(256), dim3(256), args,
                                            (unsigned)SMEM_SCAN, stream);
  if (e != hipSuccess)
    fprintf(stderr, "[kernel] coop launch failed: %d (%s)\n", (int)e, hipGetErrorString(e));

  k_out<<<256, 256, 0, stream>>>(hs, wout, bout, out);
}